// Round 11
// baseline (325.245 us; speedup 1.0000x reference)
//
#include <hip/hip_runtime.h>
#include <hip/hip_bf16.h>

// TrajectoryDecoder: B=8192 LSTM, T=128, H=128, CTX=256, IN_DIM=132.
// R21 = R20 (250us, best) + uniform phase-body reorder [loads; EW; MFMA].
// R20 post-mortem: static parity + setprio ~ -1%. Issue accounting now
// closes: per phase/SIMD ~720cy pure issue (448 trans + 160 VALU + 70
// MFMA/pred + 40 LDS) vs ~1000cy measured -> ~70% issue-bound, trans is
// the floor (5 exp + 2 rcp/elem is minimal LSTM math). Largest remaining
// stall with a mechanism: 4x ds_read_b128 A-frags issue right before the
// MFMAs that consume them (~120cy LDS latency exposed/phase) because the
// independent EW comes after the MFMAs in program order and the compiler
// won't hoist EW's sh_h writes above MFMA's sh_h reads (same array).
// Fix: reorder EVERY wave's phase to [A-loads; EW(E); MFMA(G); pred] --
// read latency hides under EW's ~300cy trans issue. Unlike R15 (half-wave
// swap -> barrier skew, regressed), this is uniform: no skew. acc[G] ->
// EW(E) dependency crosses the barrier (~covered by barrier cost).
// Everything else R20 verbatim: 512 thr, 1 block/CU, launch_bounds(512,1),
// phase-shifted A/B groups, compile-time RBUF parity, setprio on MFMA,
// direct C-seed, float2-packed EW, exp2 prescale SG={L,L,2L,L}.

#define HDIM 128
#define CTX_DIM 256
#define T_FRAMES 128
#define BB 32     // batch rows per block
#define STR 136   // h row stride (elements); 272B rows keep 16B alignment

typedef __bf16 bf16x8 __attribute__((ext_vector_type(8)));
typedef float  f32x4  __attribute__((ext_vector_type(4)));
typedef float  f32x2  __attribute__((ext_vector_type(2)));

union frag_u {
  bf16x8 v;
  unsigned short s[8];
  uint4 u4;
};

#if __has_builtin(__builtin_amdgcn_exp2f)
#define EXP2(x) __builtin_amdgcn_exp2f(x)
#else
#define EXP2(x) __expf((x) * 0.6931471805599453f)
#endif
#define RCP(x) __builtin_amdgcn_rcpf(x)

__device__ __forceinline__ unsigned short f2bf(float x) {
  unsigned u = __builtin_bit_cast(unsigned, x);
  u += 0x7FFFu + ((u >> 16) & 1u);          // RNE to bf16
  return (unsigned short)(u >> 16);
}
__device__ __forceinline__ float bf2f(unsigned short h) {
  unsigned u = ((unsigned)h) << 16;
  return __builtin_bit_cast(float, u);
}
template<int CTRL>
__device__ __forceinline__ float dpp_mov(float x) {
  return __builtin_bit_cast(float,
    __builtin_amdgcn_mov_dpp(__builtin_bit_cast(int, x), CTRL, 0xF, 0xF, true));
}
// sum over the 16-lane row group (setup-only)
__device__ __forceinline__ float row_reduce16(float v) {
  v += dpp_mov<0xB1>(v);     // quad_perm xor1
  v += dpp_mov<0x4E>(v);     // quad_perm xor2
  v += dpp_mov<0x124>(v);    // row_ror:4
  v += dpp_mov<0x128>(v);    // row_ror:8
  return v;
}

template<int N> struct Int { static constexpr int value = N; };

#define MFMA(a, b, c) __builtin_amdgcn_mfma_f32_16x16x32_bf16((a), (b), (c), 0, 0, 0)

__global__ __launch_bounds__(512, 1) void traj_lstm(
    const float* __restrict__ ctx, const float* __restrict__ enc,
    const float* __restrict__ ball,
    const float* __restrict__ Wh, const float* __restrict__ bh,
    const float* __restrict__ Wc, const float* __restrict__ bc,
    const float* __restrict__ W_ih, const float* __restrict__ W_hh,
    const float* __restrict__ b_ih, const float* __restrict__ b_hh,
    const float* __restrict__ Wo, const float* __restrict__ bo,
    float* __restrict__ outp)
{
  __shared__ __align__(16) __bf16 sh_h[2][BB * STR];          // h double buffer (17.4 KB)
  __shared__ __align__(16) unsigned short sh_sA[BB * 264];    // setup staging hi (16.9 KB)
  __shared__ __align__(16) unsigned short sh_sB[BB * 264];    // setup staging lo (16.9 KB)
  __shared__ __align__(16) uint4 sh_wof[4 * 64];              // Wo B-frags (4 KB)
  __shared__ float sh_pw0[8][BB * 2];     // setup pred partials (2 KB)
  __shared__ float sh_p0[BB * 2];         // virtual pred_{-1} for t=0 correction

  const int tid  = threadIdx.x;
  const int w    = tid >> 6;
  const int l    = tid & 63;
  const int q    = l >> 4;
  const int c16  = l & 15;
  const int colH = w * 16 + c16;
  const int rbase = blockIdx.x * BB;

  const float Lc = 1.4426950408889634f;          // log2(e)
  const float SG[4] = {Lc, Lc, 2.f * Lc, Lc};    // i, f, g, o exp2 prescales
  const float bo0 = bo[0], bo1 = bo[1];
  const float wo0 = Wo[colH], wo1 = Wo[HDIM + colH];

  // feedback weights per gate (W_prev columns)
  float wp0[4], wp1[4];
  #pragma unroll
  for (int g = 0; g < 4; ++g) {
    wp0[g] = W_ih[(size_t)(g * HDIM + colH) * 132 + 0];
    wp1[g] = W_ih[(size_t)(g * HDIM + colH) * 132 + 1];
  }

  // ---- persistent W_eff fragments: SG[g]*(W_hh + wp0*Wo0 + wp1*Wo1) ----
  frag_u Wf[4][4];                  // [gate][ktile]  (64 VGPRs)
  #pragma unroll
  for (int kt = 0; kt < 4; ++kt) {
    const float* w0p = Wo + kt * 32 + q * 8;
    const float* w1p = Wo + HDIM + kt * 32 + q * 8;
    float4 a0 = *(const float4*)w0p, a1 = *(const float4*)(w0p + 4);
    float4 b0 = *(const float4*)w1p, b1 = *(const float4*)(w1p + 4);
    float wo0v[8] = {a0.x, a0.y, a0.z, a0.w, a1.x, a1.y, a1.z, a1.w};
    float wo1v[8] = {b0.x, b0.y, b0.z, b0.w, b1.x, b1.y, b1.z, b1.w};
    #pragma unroll
    for (int g = 0; g < 4; ++g) {
      const float* wr = W_hh + (size_t)(g * HDIM + colH) * HDIM + kt * 32 + q * 8;
      float4 f0 = *(const float4*)wr;
      float4 f1 = *(const float4*)(wr + 4);
      float ff[8] = {f0.x, f0.y, f0.z, f0.w, f1.x, f1.y, f1.z, f1.w};
      #pragma unroll
      for (int j = 0; j < 8; ++j)
        Wf[g][kt].s[j] = f2bf(SG[g] * (ff[j] + wp0[g] * wo0v[j] + wp1[g] * wo1v[j]));
    }
  }

  // ---- Wo B-fragments for the pred MFMA -> LDS (waves 6/7 read) ----
  #pragma unroll
  for (int kt = 0; kt < 4; ++kt) {
    frag_u wf;
    #pragma unroll
    for (int j = 0; j < 8; ++j) {
      float x = (c16 < 2) ? Wo[c16 * HDIM + kt * 32 + q * 8 + j] : 0.f;
      wf.s[j] = f2bf(x);
    }
    if (w == 0) sh_wof[kt * 64 + l] = wf.u4;
  }

  // ---- stage context rows (32 rows, hi/lo bf16, stride 264) ----
  for (int e = tid; e < BB * 256; e += 512) {
    int row = e >> 8, col = e & 255;
    float x = ctx[(size_t)(rbase + row) * CTX_DIM + col];
    unsigned short hb = f2bf(x);
    sh_sA[row * 264 + col] = hb;
    sh_sB[row * 264 + col] = f2bf(x - bf2f(hb));
  }
  __syncthreads();

  // ---- h0/c0 = ctx @ Wh.T/Wc.T + bias (3-product split, K=256, 2 groups) ----
  float cst[2][4];   // [group][r]  (raw units)
  {
    f32x4 aH[2] = {{0.f,0.f,0.f,0.f},{0.f,0.f,0.f,0.f}};
    f32x4 aC[2] = {{0.f,0.f,0.f,0.f},{0.f,0.f,0.f,0.f}};
    #pragma unroll
    for (int kt = 0; kt < 8; ++kt) {
      frag_u Ahi[2], Alo[2];
      #pragma unroll
      for (int rt = 0; rt < 2; ++rt) {
        Ahi[rt].u4 = *(const uint4*)&sh_sA[(rt * 16 + c16) * 264 + kt * 32 + q * 8];
        Alo[rt].u4 = *(const uint4*)&sh_sB[(rt * 16 + c16) * 264 + kt * 32 + q * 8];
      }
      frag_u bhi, blo;
      {
        const float* wr = Wh + (size_t)colH * CTX_DIM + kt * 32 + q * 8;
        float4 f0 = *(const float4*)wr;
        float4 f1 = *(const float4*)(wr + 4);
        float ff[8] = {f0.x, f0.y, f0.z, f0.w, f1.x, f1.y, f1.z, f1.w};
        #pragma unroll
        for (int j = 0; j < 8; ++j) {
          unsigned short hb = f2bf(ff[j]);
          bhi.s[j] = hb;
          blo.s[j] = f2bf(ff[j] - bf2f(hb));
        }
      }
      #pragma unroll
      for (int rt = 0; rt < 2; ++rt) {
        aH[rt] = MFMA(Ahi[rt].v, bhi.v, aH[rt]);
        aH[rt] = MFMA(Alo[rt].v, bhi.v, aH[rt]);
        aH[rt] = MFMA(Ahi[rt].v, blo.v, aH[rt]);
      }
      {
        const float* wr = Wc + (size_t)colH * CTX_DIM + kt * 32 + q * 8;
        float4 f0 = *(const float4*)wr;
        float4 f1 = *(const float4*)(wr + 4);
        float ff[8] = {f0.x, f0.y, f0.z, f0.w, f1.x, f1.y, f1.z, f1.w};
        #pragma unroll
        for (int j = 0; j < 8; ++j) {
          unsigned short hb = f2bf(ff[j]);
          bhi.s[j] = hb;
          blo.s[j] = f2bf(ff[j] - bf2f(hb));
        }
      }
      #pragma unroll
      for (int rt = 0; rt < 2; ++rt) {
        aC[rt] = MFMA(Ahi[rt].v, bhi.v, aC[rt]);
        aC[rt] = MFMA(Alo[rt].v, bhi.v, aC[rt]);
        aC[rt] = MFMA(Ahi[rt].v, blo.v, aC[rt]);
      }
    }
    float bhv = bh[colH], bcv = bc[colH];
    float pp0[8][2];
    #pragma unroll
    for (int rt = 0; rt < 2; ++rt) {
      #pragma unroll
      for (int r = 0; r < 4; ++r) {
        float h0v = aH[rt][r] + bhv;
        cst[rt][r] = aC[rt][r] + bcv;
        sh_h[0][(rt * 16 + q * 4 + r) * STR + colH] = (__bf16)h0v;
        pp0[rt * 4 + r][0] = h0v * wo0;
        pp0[rt * 4 + r][1] = h0v * wo1;
      }
    }
    #pragma unroll
    for (int m = 0; m < 8; ++m) {
      pp0[m][0] = row_reduce16(pp0[m][0]);
      pp0[m][1] = row_reduce16(pp0[m][1]);
    }
    if (c16 == 0) {
      #pragma unroll
      for (int rt = 0; rt < 2; ++rt)
        #pragma unroll
        for (int r = 0; r < 4; ++r) {
          sh_pw0[w][(rt * 16 + q * 4 + r) * 2 + 0] = pp0[rt * 4 + r][0];
          sh_pw0[w][(rt * 16 + q * 4 + r) * 2 + 1] = pp0[rt * 4 + r][1];
        }
    }
  }
  __syncthreads();   // sA/sB reuse + pw0 visibility

  // ---- stage static_in = [ball(2), enc(128), pad] (32 rows, stride 168) ----
  for (int e = tid; e < BB * 168; e += 512) {
    int row = e / 168, col = e - row * 168;
    float x = (col < 2) ? ball[(size_t)(rbase + row) * 2 + col]
            : (col < 130) ? enc[(size_t)(rbase + row) * 128 + (col - 2)] : 0.f;
    unsigned short hb = f2bf(x);
    sh_sA[row * 168 + col] = hb;
    sh_sB[row * 168 + col] = f2bf(x - bf2f(hb));
  }
  // virtual pred_{-1} = h0 @ Wo.T + bo (t=0 feedback correction)
  if (tid < BB * 2) {
    float s = (tid & 1) ? bo1 : bo0;
    #pragma unroll
    for (int w2 = 0; w2 < 8; ++w2) s += sh_pw0[w2][tid];
    sh_p0[tid] = s;
  }
  __syncthreads();

  // ---- gate_static (3-product, K=160, SG-scaled) + biases, in REGISTERS ----
  f32x4 gacc[2][4] = {{{0.f,0.f,0.f,0.f},{0.f,0.f,0.f,0.f},{0.f,0.f,0.f,0.f},{0.f,0.f,0.f,0.f}},
                      {{0.f,0.f,0.f,0.f},{0.f,0.f,0.f,0.f},{0.f,0.f,0.f,0.f},{0.f,0.f,0.f,0.f}}};
  #pragma unroll
  for (int kt = 0; kt < 5; ++kt) {
    frag_u Ahi[2], Alo[2];
    #pragma unroll
    for (int rt = 0; rt < 2; ++rt) {
      Ahi[rt].u4 = *(const uint4*)&sh_sA[(rt * 16 + c16) * 168 + kt * 32 + q * 8];
      Alo[rt].u4 = *(const uint4*)&sh_sB[(rt * 16 + c16) * 168 + kt * 32 + q * 8];
    }
    #pragma unroll
    for (int g = 0; g < 4; ++g) {
      frag_u bhi, blo;
      #pragma unroll
      for (int j = 0; j < 8; ++j) {
        int kk = kt * 32 + q * 8 + j;
        float x = (kk < 130) ? SG[g] * W_ih[(size_t)(g * HDIM + colH) * 132 + 2 + kk] : 0.f;
        unsigned short hb = f2bf(x);
        bhi.s[j] = hb;
        blo.s[j] = f2bf(x - bf2f(hb));
      }
      #pragma unroll
      for (int rt = 0; rt < 2; ++rt) {
        gacc[rt][g] = MFMA(Ahi[rt].v, bhi.v, gacc[rt][g]);
        gacc[rt][g] = MFMA(Alo[rt].v, bhi.v, gacc[rt][g]);
        gacc[rt][g] = MFMA(Ahi[rt].v, blo.v, gacc[rt][g]);
      }
    }
  }
  // scaled feedback weights (t=0 correction operates in scaled units)
  float wps0[4], wps1[4];
  #pragma unroll
  for (int g = 0; g < 4; ++g) {
    int colG = g * HDIM + colH;
    float bb = SG[g] * (b_ih[colG] + b_hh[colG] + bo0 * wp0[g] + bo1 * wp1[g]);
    #pragma unroll
    for (int rt = 0; rt < 2; ++rt)
      #pragma unroll
      for (int r = 0; r < 4; ++r) gacc[rt][g][r] += bb;
    wps0[g] = SG[g] * wp0[g];
    wps1[g] = SG[g] * wp1[g];
  }

  // ---- phase-shifted time loop, compile-time parity, [loads;EW;MFMA] order ----
  f32x4 acc[2][4];

  auto phase = [&](auto GC, auto RC, int t, bool doEw, bool corr, bool doPred) {
    constexpr int G = decltype(GC)::value;
    constexpr int E = 1 - G;
    constexpr int RBUF = decltype(RC)::value;
    constexpr int WB = (RBUF + G) & 1;
    const __bf16* hp = &sh_h[RBUF][(G * 16 + c16) * STR];

    // --- (1) issue A-frag loads FIRST; latency hides under EW below
    frag_u A[4];
    #pragma unroll
    for (int kt = 0; kt < 4; ++kt)
      A[kt].u4 = *(const uint4*)(hp + kt * 32 + q * 8);

    // --- (2) elementwise for group E (independent of A / this phase's MFMAs)
    if (doEw) {
      if (corr) {  // gates at tE==0: remove folded pred_{-1} feedback (scaled)
        #pragma unroll
        for (int r = 0; r < 4; ++r) {
          float2 p0r = *(const float2*)&sh_p0[(E * 16 + q * 4 + r) * 2];
          #pragma unroll
          for (int g = 0; g < 4; ++g)
            acc[E][g][r] -= p0r.x * wps0[g] + p0r.y * wps1[g];
        }
      }
      __bf16* hwp = &sh_h[WB][(E * 16) * STR + colH];
      #pragma unroll
      for (int pr = 0; pr < 2; ++pr) {
        const int r0 = pr * 2, r1 = pr * 2 + 1;
        f32x2 ei = { EXP2(-acc[E][0][r0]), EXP2(-acc[E][0][r1]) };   // e^{-i}
        f32x2 ef = { EXP2(-acc[E][1][r0]), EXP2(-acc[E][1][r1]) };   // e^{-f}
        f32x2 eg = { EXP2(-acc[E][2][r0]), EXP2(-acc[E][2][r1]) };   // e^{-2g}
        f32x2 eo = { EXP2(-acc[E][3][r0]), EXP2(-acc[E][3][r1]) };   // e^{-o}
        f32x2 t1 = (1.f + ei) * (1.f + eg);
        f32x2 pf = 1.f + ef;
        f32x2 cp = { cst[E][r0], cst[E][r1] };
        f32x2 num = cp * t1 + (1.f - eg) * pf;
        f32x2 den = t1 * pf;
        f32x2 cv = num * (f32x2){ RCP(den.x), RCP(den.y) };
        cst[E][r0] = cv.x;
        cst[E][r1] = cv.y;
        f32x2 cc = { fmaxf(cv.x, -15.f), fmaxf(cv.y, -15.f) };       // -inf guard
        cc = cc * (-2.f * 1.4426950408889634f);
        f32x2 ec = { EXP2(cc.x), EXP2(cc.y) };
        f32x2 d2 = (1.f + eo) * (1.f + ec);
        f32x2 hv = (1.f - ec) * (f32x2){ RCP(d2.x), RCP(d2.y) };
        hwp[(q * 4 + r0) * STR] = (__bf16)hv.x;
        hwp[(q * 4 + r1) * STR] = (__bf16)hv.y;
      }
    }

    // --- (3) MFMA gates for group G at time t; kt=0 consumes seed directly
    __builtin_amdgcn_s_setprio(1);
    #pragma unroll
    for (int g = 0; g < 4; ++g)
      acc[G][g] = MFMA(A[0].v, Wf[g][0].v, gacc[G][g]);
    #pragma unroll
    for (int kt = 1; kt < 4; ++kt)
      #pragma unroll
      for (int g = 0; g < 4; ++g)
        acc[G][g] = MFMA(A[kt].v, Wf[g][kt].v, acc[G][g]);

    // --- (4) pred[t-1] rows G = h_G(t) @ Wo (wave 6 for A, wave 7 for B)
    if (doPred && w == 6 + G) {
      f32x4 accP = {0.f, 0.f, 0.f, 0.f};
      #pragma unroll
      for (int kt = 0; kt < 4; ++kt) {
        frag_u wof;
        wof.u4 = sh_wof[kt * 64 + l];
        accP = MFMA(A[kt].v, wof.v, accP);
      }
      if (c16 < 2) {
        const int m0 = G * 16 + q * 4;
        const float bov = c16 ? bo1 : bo0;
        #pragma unroll
        for (int r = 0; r < 4; ++r)
          outp[(size_t)(rbase + m0 + r) * (T_FRAMES * 2) + (t - 1) * 2 + c16] = accP[r] + bov;
      }
    }
    __builtin_amdgcn_s_setprio(0);
    __syncthreads();
  };

  phase(Int<0>{}, Int<0>{}, 0, false, false, false);   // MFMA A(0)
  phase(Int<1>{}, Int<0>{}, 0, true,  true,  false);   // MFMA B(0); ew A(0)+corr -> h_A(1)
  phase(Int<0>{}, Int<1>{}, 1, true,  true,  true);    // MFMA A(1); ew B(0)+corr -> h_B(1); pred[0]A
  for (int tp = 0; tp < 63; ++tp) {
    const int t = 2 * tp + 1;
    phase(Int<1>{}, Int<1>{}, t,     true, false, true);   // MFMA B(t);   ew A(t)   -> h_A(t+1)
    phase(Int<0>{}, Int<0>{}, t + 1, true, false, true);   // MFMA A(t+1); ew B(t)   -> h_B(t+1)
    phase(Int<1>{}, Int<0>{}, t + 1, true, false, true);   // MFMA B(t+1); ew A(t+1) -> h_A(t+2)
    phase(Int<0>{}, Int<1>{}, t + 2, true, false, true);   // MFMA A(t+2); ew B(t+1) -> h_B(t+2)
  }
  phase(Int<1>{}, Int<1>{}, 127, true, false, true);   // MFMA B(127); ew A(127) -> h_A(128); pred[126]B

  // final elementwise: B(127) -> h_B(128) into buf[0]
  {
    __bf16* hwp = &sh_h[0][16 * STR + colH];
    #pragma unroll
    for (int r = 0; r < 4; ++r) {
      float ei = EXP2(-acc[1][0][r]);
      float ef = EXP2(-acc[1][1][r]);
      float eg = EXP2(-acc[1][2][r]);
      float eo = EXP2(-acc[1][3][r]);
      float t1 = (1.f + ei) * (1.f + eg);
      float pf = 1.f + ef;
      float num = cst[1][r] * t1 + (1.f - eg) * pf;
      float cv = num * RCP(t1 * pf);
      float cc = fmaxf(cv, -15.f);
      float ec = EXP2(cc * (-2.f * 1.4426950408889634f));
      float hv = (1.f - ec) * RCP((1.f + eo) * (1.f + ec));
      hwp[(q * 4 + r) * STR] = (__bf16)hv;
    }
  }
  __syncthreads();

  // ---- epilogue: pred[127] from h(128) (buf 0), waves 6 (A) / 7 (B) ----
  if (w == 6 || w == 7) {
    const int Ge = w - 6;
    const __bf16* hp = &sh_h[0][(Ge * 16 + c16) * STR];
    f32x4 accP = {0.f, 0.f, 0.f, 0.f};
    #pragma unroll
    for (int kt = 0; kt < 4; ++kt) {
      frag_u A, wof;
      A.u4 = *(const uint4*)(hp + kt * 32 + q * 8);
      wof.u4 = sh_wof[kt * 64 + l];
      accP = MFMA(A.v, wof.v, accP);
    }
    if (c16 < 2) {
      const int m0 = Ge * 16 + q * 4;
      const float bov = c16 ? bo1 : bo0;
      #pragma unroll
      for (int r = 0; r < 4; ++r)
        outp[(size_t)(rbase + m0 + r) * (T_FRAMES * 2) + 127 * 2 + c16] = accP[r] + bov;
    }
  }
}

extern "C" void kernel_launch(void* const* d_in, const int* in_sizes, int n_in,
                              void* d_out, int out_size, void* d_ws, size_t ws_size,
                              hipStream_t stream) {
  (void)in_sizes; (void)n_in; (void)d_ws; (void)ws_size; (void)out_size;
  const float* ctx  = (const float*)d_in[0];
  const float* enc  = (const float*)d_in[1];
  const float* ball = (const float*)d_in[2];
  // d_in[3] = max_frames (always 128)
  const float* Wh   = (const float*)d_in[4];
  const float* bh   = (const float*)d_in[5];
  const float* Wc   = (const float*)d_in[6];
  const float* bc   = (const float*)d_in[7];
  const float* W_ih = (const float*)d_in[8];
  const float* W_hh = (const float*)d_in[9];
  const float* b_ih = (const float*)d_in[10];
  const float* b_hh = (const float*)d_in[11];
  const float* Wo   = (const float*)d_in[12];
  const float* bo   = (const float*)d_in[13];
  float* outp = (float*)d_out;

  dim3 grid(256), block(512);
  traj_lstm<<<grid, block, 0, stream>>>(ctx, enc, ball, Wh, bh, Wc, bc,
                                        W_ih, W_hh, b_ih, b_hh, Wo, bo, outp);
}

// Round 12
// 310.979 us; speedup vs baseline: 1.0459x; 1.0459x over previous
//
#include <hip/hip_runtime.h>
#include <hip/hip_bf16.h>

// TrajectoryDecoder: B=8192 LSTM, T=128, H=128, CTX=256, IN_DIM=132.
// R22 = R20 (best, 249-253us steady) + uniform pred (WoF in registers).
// R21 post-mortem: [loads;EW;MFMA] reorder REGRESSED (280us, VALUBusy
// 46->40): EW's ds_writes between A-reads and MFMAs force a conservative
// lgkmcnt drain (LDS ops complete in order) -> serialized. Reverted to
// R20's [loads;MFMA;pred;EW] order.
// This round removes the per-phase straggler: waves 6/7 ran +4 pred-MFMAs
// + 4 ds_read_b128 (WoF from LDS) ~= +70cy that all 8 waves inherit at the
// barrier, 255 times. Fix: WoF held in REGISTERS on every wave (+16 VGPR,
// headroom 128/256); ALL waves compute the 4-MFMA accP chain (A-frags are
// identical across waves -> redundant but uniform, +20cy); only wave 6+G
// stores. Net ~-50cy/phase. sh_wof LDS array deleted.
// Everything else R20 verbatim: 512 thr, 1 block/CU, launch_bounds(512,1),
// phase-shifted A/B groups, compile-time RBUF parity, setprio on MFMA,
// direct C-seed, float2-packed EW, exp2 prescale SG={L,L,2L,L}.

#define HDIM 128
#define CTX_DIM 256
#define T_FRAMES 128
#define BB 32     // batch rows per block
#define STR 136   // h row stride (elements); 272B rows keep 16B alignment

typedef __bf16 bf16x8 __attribute__((ext_vector_type(8)));
typedef float  f32x4  __attribute__((ext_vector_type(4)));
typedef float  f32x2  __attribute__((ext_vector_type(2)));

union frag_u {
  bf16x8 v;
  unsigned short s[8];
  uint4 u4;
};

#if __has_builtin(__builtin_amdgcn_exp2f)
#define EXP2(x) __builtin_amdgcn_exp2f(x)
#else
#define EXP2(x) __expf((x) * 0.6931471805599453f)
#endif
#define RCP(x) __builtin_amdgcn_rcpf(x)

__device__ __forceinline__ unsigned short f2bf(float x) {
  unsigned u = __builtin_bit_cast(unsigned, x);
  u += 0x7FFFu + ((u >> 16) & 1u);          // RNE to bf16
  return (unsigned short)(u >> 16);
}
__device__ __forceinline__ float bf2f(unsigned short h) {
  unsigned u = ((unsigned)h) << 16;
  return __builtin_bit_cast(float, u);
}
template<int CTRL>
__device__ __forceinline__ float dpp_mov(float x) {
  return __builtin_bit_cast(float,
    __builtin_amdgcn_mov_dpp(__builtin_bit_cast(int, x), CTRL, 0xF, 0xF, true));
}
// sum over the 16-lane row group (setup-only)
__device__ __forceinline__ float row_reduce16(float v) {
  v += dpp_mov<0xB1>(v);     // quad_perm xor1
  v += dpp_mov<0x4E>(v);     // quad_perm xor2
  v += dpp_mov<0x124>(v);    // row_ror:4
  v += dpp_mov<0x128>(v);    // row_ror:8
  return v;
}

template<int N> struct Int { static constexpr int value = N; };

#define MFMA(a, b, c) __builtin_amdgcn_mfma_f32_16x16x32_bf16((a), (b), (c), 0, 0, 0)

__global__ __launch_bounds__(512, 1) void traj_lstm(
    const float* __restrict__ ctx, const float* __restrict__ enc,
    const float* __restrict__ ball,
    const float* __restrict__ Wh, const float* __restrict__ bh,
    const float* __restrict__ Wc, const float* __restrict__ bc,
    const float* __restrict__ W_ih, const float* __restrict__ W_hh,
    const float* __restrict__ b_ih, const float* __restrict__ b_hh,
    const float* __restrict__ Wo, const float* __restrict__ bo,
    float* __restrict__ outp)
{
  __shared__ __align__(16) __bf16 sh_h[2][BB * STR];          // h double buffer (17.4 KB)
  __shared__ __align__(16) unsigned short sh_sA[BB * 264];    // setup staging hi (16.9 KB)
  __shared__ __align__(16) unsigned short sh_sB[BB * 264];    // setup staging lo (16.9 KB)
  __shared__ float sh_pw0[8][BB * 2];     // setup pred partials (2 KB)
  __shared__ float sh_p0[BB * 2];         // virtual pred_{-1} for t=0 correction

  const int tid  = threadIdx.x;
  const int w    = tid >> 6;
  const int l    = tid & 63;
  const int q    = l >> 4;
  const int c16  = l & 15;
  const int colH = w * 16 + c16;
  const int rbase = blockIdx.x * BB;

  const float Lc = 1.4426950408889634f;          // log2(e)
  const float SG[4] = {Lc, Lc, 2.f * Lc, Lc};    // i, f, g, o exp2 prescales
  const float bo0 = bo[0], bo1 = bo[1];
  const float wo0 = Wo[colH], wo1 = Wo[HDIM + colH];

  // feedback weights per gate (W_prev columns)
  float wp0[4], wp1[4];
  #pragma unroll
  for (int g = 0; g < 4; ++g) {
    wp0[g] = W_ih[(size_t)(g * HDIM + colH) * 132 + 0];
    wp1[g] = W_ih[(size_t)(g * HDIM + colH) * 132 + 1];
  }

  // ---- persistent W_eff fragments: SG[g]*(W_hh + wp0*Wo0 + wp1*Wo1) ----
  frag_u Wf[4][4];                  // [gate][ktile]  (64 VGPRs)
  #pragma unroll
  for (int kt = 0; kt < 4; ++kt) {
    const float* w0p = Wo + kt * 32 + q * 8;
    const float* w1p = Wo + HDIM + kt * 32 + q * 8;
    float4 a0 = *(const float4*)w0p, a1 = *(const float4*)(w0p + 4);
    float4 b0 = *(const float4*)w1p, b1 = *(const float4*)(w1p + 4);
    float wo0v[8] = {a0.x, a0.y, a0.z, a0.w, a1.x, a1.y, a1.z, a1.w};
    float wo1v[8] = {b0.x, b0.y, b0.z, b0.w, b1.x, b1.y, b1.z, b1.w};
    #pragma unroll
    for (int g = 0; g < 4; ++g) {
      const float* wr = W_hh + (size_t)(g * HDIM + colH) * HDIM + kt * 32 + q * 8;
      float4 f0 = *(const float4*)wr;
      float4 f1 = *(const float4*)(wr + 4);
      float ff[8] = {f0.x, f0.y, f0.z, f0.w, f1.x, f1.y, f1.z, f1.w};
      #pragma unroll
      for (int j = 0; j < 8; ++j)
        Wf[g][kt].s[j] = f2bf(SG[g] * (ff[j] + wp0[g] * wo0v[j] + wp1[g] * wo1v[j]));
    }
  }

  // ---- Wo B-fragments for the pred MFMA: REGISTERS on every wave ----
  frag_u WoF[4];                    // (16 VGPRs)
  #pragma unroll
  for (int kt = 0; kt < 4; ++kt) {
    #pragma unroll
    for (int j = 0; j < 8; ++j) {
      float x = (c16 < 2) ? Wo[c16 * HDIM + kt * 32 + q * 8 + j] : 0.f;
      WoF[kt].s[j] = f2bf(x);
    }
  }

  // ---- stage context rows (32 rows, hi/lo bf16, stride 264) ----
  for (int e = tid; e < BB * 256; e += 512) {
    int row = e >> 8, col = e & 255;
    float x = ctx[(size_t)(rbase + row) * CTX_DIM + col];
    unsigned short hb = f2bf(x);
    sh_sA[row * 264 + col] = hb;
    sh_sB[row * 264 + col] = f2bf(x - bf2f(hb));
  }
  __syncthreads();

  // ---- h0/c0 = ctx @ Wh.T/Wc.T + bias (3-product split, K=256, 2 groups) ----
  float cst[2][4];   // [group][r]  (raw units)
  {
    f32x4 aH[2] = {{0.f,0.f,0.f,0.f},{0.f,0.f,0.f,0.f}};
    f32x4 aC[2] = {{0.f,0.f,0.f,0.f},{0.f,0.f,0.f,0.f}};
    #pragma unroll
    for (int kt = 0; kt < 8; ++kt) {
      frag_u Ahi[2], Alo[2];
      #pragma unroll
      for (int rt = 0; rt < 2; ++rt) {
        Ahi[rt].u4 = *(const uint4*)&sh_sA[(rt * 16 + c16) * 264 + kt * 32 + q * 8];
        Alo[rt].u4 = *(const uint4*)&sh_sB[(rt * 16 + c16) * 264 + kt * 32 + q * 8];
      }
      frag_u bhi, blo;
      {
        const float* wr = Wh + (size_t)colH * CTX_DIM + kt * 32 + q * 8;
        float4 f0 = *(const float4*)wr;
        float4 f1 = *(const float4*)(wr + 4);
        float ff[8] = {f0.x, f0.y, f0.z, f0.w, f1.x, f1.y, f1.z, f1.w};
        #pragma unroll
        for (int j = 0; j < 8; ++j) {
          unsigned short hb = f2bf(ff[j]);
          bhi.s[j] = hb;
          blo.s[j] = f2bf(ff[j] - bf2f(hb));
        }
      }
      #pragma unroll
      for (int rt = 0; rt < 2; ++rt) {
        aH[rt] = MFMA(Ahi[rt].v, bhi.v, aH[rt]);
        aH[rt] = MFMA(Alo[rt].v, bhi.v, aH[rt]);
        aH[rt] = MFMA(Ahi[rt].v, blo.v, aH[rt]);
      }
      {
        const float* wr = Wc + (size_t)colH * CTX_DIM + kt * 32 + q * 8;
        float4 f0 = *(const float4*)wr;
        float4 f1 = *(const float4*)(wr + 4);
        float ff[8] = {f0.x, f0.y, f0.z, f0.w, f1.x, f1.y, f1.z, f1.w};
        #pragma unroll
        for (int j = 0; j < 8; ++j) {
          unsigned short hb = f2bf(ff[j]);
          bhi.s[j] = hb;
          blo.s[j] = f2bf(ff[j] - bf2f(hb));
        }
      }
      #pragma unroll
      for (int rt = 0; rt < 2; ++rt) {
        aC[rt] = MFMA(Ahi[rt].v, bhi.v, aC[rt]);
        aC[rt] = MFMA(Alo[rt].v, bhi.v, aC[rt]);
        aC[rt] = MFMA(Ahi[rt].v, blo.v, aC[rt]);
      }
    }
    float bhv = bh[colH], bcv = bc[colH];
    float pp0[8][2];
    #pragma unroll
    for (int rt = 0; rt < 2; ++rt) {
      #pragma unroll
      for (int r = 0; r < 4; ++r) {
        float h0v = aH[rt][r] + bhv;
        cst[rt][r] = aC[rt][r] + bcv;
        sh_h[0][(rt * 16 + q * 4 + r) * STR + colH] = (__bf16)h0v;
        pp0[rt * 4 + r][0] = h0v * wo0;
        pp0[rt * 4 + r][1] = h0v * wo1;
      }
    }
    #pragma unroll
    for (int m = 0; m < 8; ++m) {
      pp0[m][0] = row_reduce16(pp0[m][0]);
      pp0[m][1] = row_reduce16(pp0[m][1]);
    }
    if (c16 == 0) {
      #pragma unroll
      for (int rt = 0; rt < 2; ++rt)
        #pragma unroll
        for (int r = 0; r < 4; ++r) {
          sh_pw0[w][(rt * 16 + q * 4 + r) * 2 + 0] = pp0[rt * 4 + r][0];
          sh_pw0[w][(rt * 16 + q * 4 + r) * 2 + 1] = pp0[rt * 4 + r][1];
        }
    }
  }
  __syncthreads();   // sA/sB reuse + pw0 visibility

  // ---- stage static_in = [ball(2), enc(128), pad] (32 rows, stride 168) ----
  for (int e = tid; e < BB * 168; e += 512) {
    int row = e / 168, col = e - row * 168;
    float x = (col < 2) ? ball[(size_t)(rbase + row) * 2 + col]
            : (col < 130) ? enc[(size_t)(rbase + row) * 128 + (col - 2)] : 0.f;
    unsigned short hb = f2bf(x);
    sh_sA[row * 168 + col] = hb;
    sh_sB[row * 168 + col] = f2bf(x - bf2f(hb));
  }
  // virtual pred_{-1} = h0 @ Wo.T + bo (t=0 feedback correction)
  if (tid < BB * 2) {
    float s = (tid & 1) ? bo1 : bo0;
    #pragma unroll
    for (int w2 = 0; w2 < 8; ++w2) s += sh_pw0[w2][tid];
    sh_p0[tid] = s;
  }
  __syncthreads();

  // ---- gate_static (3-product, K=160, SG-scaled) + biases, in REGISTERS ----
  f32x4 gacc[2][4] = {{{0.f,0.f,0.f,0.f},{0.f,0.f,0.f,0.f},{0.f,0.f,0.f,0.f},{0.f,0.f,0.f,0.f}},
                      {{0.f,0.f,0.f,0.f},{0.f,0.f,0.f,0.f},{0.f,0.f,0.f,0.f},{0.f,0.f,0.f,0.f}}};
  #pragma unroll
  for (int kt = 0; kt < 5; ++kt) {
    frag_u Ahi[2], Alo[2];
    #pragma unroll
    for (int rt = 0; rt < 2; ++rt) {
      Ahi[rt].u4 = *(const uint4*)&sh_sA[(rt * 16 + c16) * 168 + kt * 32 + q * 8];
      Alo[rt].u4 = *(const uint4*)&sh_sB[(rt * 16 + c16) * 168 + kt * 32 + q * 8];
    }
    #pragma unroll
    for (int g = 0; g < 4; ++g) {
      frag_u bhi, blo;
      #pragma unroll
      for (int j = 0; j < 8; ++j) {
        int kk = kt * 32 + q * 8 + j;
        float x = (kk < 130) ? SG[g] * W_ih[(size_t)(g * HDIM + colH) * 132 + 2 + kk] : 0.f;
        unsigned short hb = f2bf(x);
        bhi.s[j] = hb;
        blo.s[j] = f2bf(x - bf2f(hb));
      }
      #pragma unroll
      for (int rt = 0; rt < 2; ++rt) {
        gacc[rt][g] = MFMA(Ahi[rt].v, bhi.v, gacc[rt][g]);
        gacc[rt][g] = MFMA(Alo[rt].v, bhi.v, gacc[rt][g]);
        gacc[rt][g] = MFMA(Ahi[rt].v, blo.v, gacc[rt][g]);
      }
    }
  }
  // scaled feedback weights (t=0 correction operates in scaled units)
  float wps0[4], wps1[4];
  #pragma unroll
  for (int g = 0; g < 4; ++g) {
    int colG = g * HDIM + colH;
    float bb = SG[g] * (b_ih[colG] + b_hh[colG] + bo0 * wp0[g] + bo1 * wp1[g]);
    #pragma unroll
    for (int rt = 0; rt < 2; ++rt)
      #pragma unroll
      for (int r = 0; r < 4; ++r) gacc[rt][g][r] += bb;
    wps0[g] = SG[g] * wp0[g];
    wps1[g] = SG[g] * wp1[g];
  }

  // ---- phase-shifted time loop, compile-time parity, R20 order ----
  f32x4 acc[2][4];

  auto phase = [&](auto GC, auto RC, int t, bool doEw, bool corr, bool doPred) {
    constexpr int G = decltype(GC)::value;
    constexpr int E = 1 - G;
    constexpr int RBUF = decltype(RC)::value;
    constexpr int WB = (RBUF + G) & 1;
    const __bf16* hp = &sh_h[RBUF][(G * 16 + c16) * STR];

    // --- MFMA gates for group G at time t; kt=0 consumes gate_static seed
    //     DIRECTLY as the MFMA C operand (no register copy).
    frag_u A[4];
    #pragma unroll
    for (int kt = 0; kt < 4; ++kt)
      A[kt].u4 = *(const uint4*)(hp + kt * 32 + q * 8);
    __builtin_amdgcn_s_setprio(1);
    #pragma unroll
    for (int g = 0; g < 4; ++g)
      acc[G][g] = MFMA(A[0].v, Wf[g][0].v, gacc[G][g]);
    #pragma unroll
    for (int kt = 1; kt < 4; ++kt)
      #pragma unroll
      for (int g = 0; g < 4; ++g)
        acc[G][g] = MFMA(A[kt].v, Wf[g][kt].v, acc[G][g]);

    // --- pred[t-1] rows G = h_G(t) @ Wo: UNIFORM on all waves (A-frags are
    //     identical across waves; WoF in registers). Only wave 6+G stores.
    if (doPred) {
      f32x4 accP = {0.f, 0.f, 0.f, 0.f};
      #pragma unroll
      for (int kt = 0; kt < 4; ++kt)
        accP = MFMA(A[kt].v, WoF[kt].v, accP);
      if (w == 6 + G && c16 < 2) {
        const int m0 = G * 16 + q * 4;
        const float bov = c16 ? bo1 : bo0;
        #pragma unroll
        for (int r = 0; r < 4; ++r)
          outp[(size_t)(rbase + m0 + r) * (T_FRAMES * 2) + (t - 1) * 2 + c16] = accP[r] + bov;
      }
    }
    __builtin_amdgcn_s_setprio(0);

    // --- elementwise for group E (independent of this phase's MFMAs)
    //     trans scalar, algebra packed as float2 pairs (v_pk_* on gfx950)
    if (doEw) {
      if (corr) {  // gates at tE==0: remove folded pred_{-1} feedback (scaled)
        #pragma unroll
        for (int r = 0; r < 4; ++r) {
          float2 p0r = *(const float2*)&sh_p0[(E * 16 + q * 4 + r) * 2];
          #pragma unroll
          for (int g = 0; g < 4; ++g)
            acc[E][g][r] -= p0r.x * wps0[g] + p0r.y * wps1[g];
        }
      }
      __bf16* hwp = &sh_h[WB][(E * 16) * STR + colH];
      #pragma unroll
      for (int pr = 0; pr < 2; ++pr) {
        const int r0 = pr * 2, r1 = pr * 2 + 1;
        f32x2 ei = { EXP2(-acc[E][0][r0]), EXP2(-acc[E][0][r1]) };   // e^{-i}
        f32x2 ef = { EXP2(-acc[E][1][r0]), EXP2(-acc[E][1][r1]) };   // e^{-f}
        f32x2 eg = { EXP2(-acc[E][2][r0]), EXP2(-acc[E][2][r1]) };   // e^{-2g}
        f32x2 eo = { EXP2(-acc[E][3][r0]), EXP2(-acc[E][3][r1]) };   // e^{-o}
        f32x2 t1 = (1.f + ei) * (1.f + eg);
        f32x2 pf = 1.f + ef;
        f32x2 cp = { cst[E][r0], cst[E][r1] };
        f32x2 num = cp * t1 + (1.f - eg) * pf;
        f32x2 den = t1 * pf;
        f32x2 cv = num * (f32x2){ RCP(den.x), RCP(den.y) };
        cst[E][r0] = cv.x;
        cst[E][r1] = cv.y;
        f32x2 cc = { fmaxf(cv.x, -15.f), fmaxf(cv.y, -15.f) };       // -inf guard
        cc = cc * (-2.f * 1.4426950408889634f);
        f32x2 ec = { EXP2(cc.x), EXP2(cc.y) };
        f32x2 d2 = (1.f + eo) * (1.f + ec);
        f32x2 hv = (1.f - ec) * (f32x2){ RCP(d2.x), RCP(d2.y) };
        hwp[(q * 4 + r0) * STR] = (__bf16)hv.x;
        hwp[(q * 4 + r1) * STR] = (__bf16)hv.y;
      }
    }
    __syncthreads();
  };

  phase(Int<0>{}, Int<0>{}, 0, false, false, false);   // MFMA A(0)
  phase(Int<1>{}, Int<0>{}, 0, true,  true,  false);   // MFMA B(0); ew A(0)+corr -> h_A(1)
  phase(Int<0>{}, Int<1>{}, 1, true,  true,  true);    // MFMA A(1); ew B(0)+corr -> h_B(1); pred[0]A
  for (int tp = 0; tp < 63; ++tp) {
    const int t = 2 * tp + 1;
    phase(Int<1>{}, Int<1>{}, t,     true, false, true);   // MFMA B(t);   ew A(t)   -> h_A(t+1)
    phase(Int<0>{}, Int<0>{}, t + 1, true, false, true);   // MFMA A(t+1); ew B(t)   -> h_B(t+1)
    phase(Int<1>{}, Int<0>{}, t + 1, true, false, true);   // MFMA B(t+1); ew A(t+1) -> h_A(t+2)
    phase(Int<0>{}, Int<1>{}, t + 2, true, false, true);   // MFMA A(t+2); ew B(t+1) -> h_B(t+2)
  }
  phase(Int<1>{}, Int<1>{}, 127, true, false, true);   // MFMA B(127); ew A(127) -> h_A(128); pred[126]B

  // final elementwise: B(127) -> h_B(128) into buf[0]
  {
    __bf16* hwp = &sh_h[0][16 * STR + colH];
    #pragma unroll
    for (int r = 0; r < 4; ++r) {
      float ei = EXP2(-acc[1][0][r]);
      float ef = EXP2(-acc[1][1][r]);
      float eg = EXP2(-acc[1][2][r]);
      float eo = EXP2(-acc[1][3][r]);
      float t1 = (1.f + ei) * (1.f + eg);
      float pf = 1.f + ef;
      float num = cst[1][r] * t1 + (1.f - eg) * pf;
      float cv = num * RCP(t1 * pf);
      float cc = fmaxf(cv, -15.f);
      float ec = EXP2(cc * (-2.f * 1.4426950408889634f));
      float hv = (1.f - ec) * RCP((1.f + eo) * (1.f + ec));
      hwp[(q * 4 + r) * STR] = (__bf16)hv;
    }
  }
  __syncthreads();

  // ---- epilogue: pred[127] from h(128) (buf 0), waves 6 (A) / 7 (B) ----
  if (w == 6 || w == 7) {
    const int Ge = w - 6;
    const __bf16* hp = &sh_h[0][(Ge * 16 + c16) * STR];
    f32x4 accP = {0.f, 0.f, 0.f, 0.f};
    #pragma unroll
    for (int kt = 0; kt < 4; ++kt) {
      frag_u A;
      A.u4 = *(const uint4*)(hp + kt * 32 + q * 8);
      accP = MFMA(A.v, WoF[kt].v, accP);
    }
    if (c16 < 2) {
      const int m0 = Ge * 16 + q * 4;
      const float bov = c16 ? bo1 : bo0;
      #pragma unroll
      for (int r = 0; r < 4; ++r)
        outp[(size_t)(rbase + m0 + r) * (T_FRAMES * 2) + 127 * 2 + c16] = accP[r] + bov;
    }
  }
}

extern "C" void kernel_launch(void* const* d_in, const int* in_sizes, int n_in,
                              void* d_out, int out_size, void* d_ws, size_t ws_size,
                              hipStream_t stream) {
  (void)in_sizes; (void)n_in; (void)d_ws; (void)ws_size; (void)out_size;
  const float* ctx  = (const float*)d_in[0];
  const float* enc  = (const float*)d_in[1];
  const float* ball = (const float*)d_in[2];
  // d_in[3] = max_frames (always 128)
  const float* Wh   = (const float*)d_in[4];
  const float* bh   = (const float*)d_in[5];
  const float* Wc   = (const float*)d_in[6];
  const float* bc   = (const float*)d_in[7];
  const float* W_ih = (const float*)d_in[8];
  const float* W_hh = (const float*)d_in[9];
  const float* b_ih = (const float*)d_in[10];
  const float* b_hh = (const float*)d_in[11];
  const float* Wo   = (const float*)d_in[12];
  const float* bo   = (const float*)d_in[13];
  float* outp = (float*)d_out;

  dim3 grid(256), block(512);
  traj_lstm<<<grid, block, 0, stream>>>(ctx, enc, ball, Wh, bh, Wc, bc,
                                        W_ih, W_hh, b_ih, b_hh, Wo, bo, outp);
}

// Round 13
// 295.816 us; speedup vs baseline: 1.0995x; 1.0513x over previous
//
#include <hip/hip_runtime.h>
#include <hip/hip_bf16.h>

// TrajectoryDecoder: B=8192 LSTM, T=128, H=128, CTX=256, IN_DIM=132.
// R23 = exact revert to R20 (session best: 249-253us steady).
// R22 post-mortem: WoF-in-regs + uniform pred pushed past the allocator's
// hard 128-reg working set -> loop-carried scratch (WRITE 37->53MB), 297us.
// R21 post-mortem: [loads;EW;MFMA] reorder -> lgkmcnt drain serialization.
// Ledger of refuted levers: occupancy x2/x4 (R11/R12/R16/R17), barrier
// domains (R17), producer/consumer waves (R14), intra-wave reorder
// (R13/R15/R21), store-drain removal (R18), reg expansion (R22).
// Wins: VALU-count cuts only (R19 packed-EW/direct-C-seed -7us, R20
// static-parity/setprio -3us). Residual = serial phase dependency
// (ds_read -> 4-deep MFMA -> 7-trans EW -> barrier) at 2 waves/SIMD,
// trans chain mathematically minimal. This is the consolidation round.

#define HDIM 128
#define CTX_DIM 256
#define T_FRAMES 128
#define BB 32     // batch rows per block
#define STR 136   // h row stride (elements); 272B rows keep 16B alignment

typedef __bf16 bf16x8 __attribute__((ext_vector_type(8)));
typedef float  f32x4  __attribute__((ext_vector_type(4)));
typedef float  f32x2  __attribute__((ext_vector_type(2)));

union frag_u {
  bf16x8 v;
  unsigned short s[8];
  uint4 u4;
};

#if __has_builtin(__builtin_amdgcn_exp2f)
#define EXP2(x) __builtin_amdgcn_exp2f(x)
#else
#define EXP2(x) __expf((x) * 0.6931471805599453f)
#endif
#define RCP(x) __builtin_amdgcn_rcpf(x)

__device__ __forceinline__ unsigned short f2bf(float x) {
  unsigned u = __builtin_bit_cast(unsigned, x);
  u += 0x7FFFu + ((u >> 16) & 1u);          // RNE to bf16
  return (unsigned short)(u >> 16);
}
__device__ __forceinline__ float bf2f(unsigned short h) {
  unsigned u = ((unsigned)h) << 16;
  return __builtin_bit_cast(float, u);
}
template<int CTRL>
__device__ __forceinline__ float dpp_mov(float x) {
  return __builtin_bit_cast(float,
    __builtin_amdgcn_mov_dpp(__builtin_bit_cast(int, x), CTRL, 0xF, 0xF, true));
}
// sum over the 16-lane row group (setup-only)
__device__ __forceinline__ float row_reduce16(float v) {
  v += dpp_mov<0xB1>(v);     // quad_perm xor1
  v += dpp_mov<0x4E>(v);     // quad_perm xor2
  v += dpp_mov<0x124>(v);    // row_ror:4
  v += dpp_mov<0x128>(v);    // row_ror:8
  return v;
}

template<int N> struct Int { static constexpr int value = N; };

#define MFMA(a, b, c) __builtin_amdgcn_mfma_f32_16x16x32_bf16((a), (b), (c), 0, 0, 0)

__global__ __launch_bounds__(512, 1) void traj_lstm(
    const float* __restrict__ ctx, const float* __restrict__ enc,
    const float* __restrict__ ball,
    const float* __restrict__ Wh, const float* __restrict__ bh,
    const float* __restrict__ Wc, const float* __restrict__ bc,
    const float* __restrict__ W_ih, const float* __restrict__ W_hh,
    const float* __restrict__ b_ih, const float* __restrict__ b_hh,
    const float* __restrict__ Wo, const float* __restrict__ bo,
    float* __restrict__ outp)
{
  __shared__ __align__(16) __bf16 sh_h[2][BB * STR];          // h double buffer (17.4 KB)
  __shared__ __align__(16) unsigned short sh_sA[BB * 264];    // setup staging hi (16.9 KB)
  __shared__ __align__(16) unsigned short sh_sB[BB * 264];    // setup staging lo (16.9 KB)
  __shared__ __align__(16) uint4 sh_wof[4 * 64];              // Wo B-frags (4 KB)
  __shared__ float sh_pw0[8][BB * 2];     // setup pred partials (2 KB)
  __shared__ float sh_p0[BB * 2];         // virtual pred_{-1} for t=0 correction

  const int tid  = threadIdx.x;
  const int w    = tid >> 6;
  const int l    = tid & 63;
  const int q    = l >> 4;
  const int c16  = l & 15;
  const int colH = w * 16 + c16;
  const int rbase = blockIdx.x * BB;

  const float Lc = 1.4426950408889634f;          // log2(e)
  const float SG[4] = {Lc, Lc, 2.f * Lc, Lc};    // i, f, g, o exp2 prescales
  const float bo0 = bo[0], bo1 = bo[1];
  const float wo0 = Wo[colH], wo1 = Wo[HDIM + colH];

  // feedback weights per gate (W_prev columns)
  float wp0[4], wp1[4];
  #pragma unroll
  for (int g = 0; g < 4; ++g) {
    wp0[g] = W_ih[(size_t)(g * HDIM + colH) * 132 + 0];
    wp1[g] = W_ih[(size_t)(g * HDIM + colH) * 132 + 1];
  }

  // ---- persistent W_eff fragments: SG[g]*(W_hh + wp0*Wo0 + wp1*Wo1) ----
  frag_u Wf[4][4];                  // [gate][ktile]  (64 VGPRs)
  #pragma unroll
  for (int kt = 0; kt < 4; ++kt) {
    const float* w0p = Wo + kt * 32 + q * 8;
    const float* w1p = Wo + HDIM + kt * 32 + q * 8;
    float4 a0 = *(const float4*)w0p, a1 = *(const float4*)(w0p + 4);
    float4 b0 = *(const float4*)w1p, b1 = *(const float4*)(w1p + 4);
    float wo0v[8] = {a0.x, a0.y, a0.z, a0.w, a1.x, a1.y, a1.z, a1.w};
    float wo1v[8] = {b0.x, b0.y, b0.z, b0.w, b1.x, b1.y, b1.z, b1.w};
    #pragma unroll
    for (int g = 0; g < 4; ++g) {
      const float* wr = W_hh + (size_t)(g * HDIM + colH) * HDIM + kt * 32 + q * 8;
      float4 f0 = *(const float4*)wr;
      float4 f1 = *(const float4*)(wr + 4);
      float ff[8] = {f0.x, f0.y, f0.z, f0.w, f1.x, f1.y, f1.z, f1.w};
      #pragma unroll
      for (int j = 0; j < 8; ++j)
        Wf[g][kt].s[j] = f2bf(SG[g] * (ff[j] + wp0[g] * wo0v[j] + wp1[g] * wo1v[j]));
    }
  }

  // ---- Wo B-fragments for the pred MFMA -> LDS (waves 6/7 read) ----
  #pragma unroll
  for (int kt = 0; kt < 4; ++kt) {
    frag_u wf;
    #pragma unroll
    for (int j = 0; j < 8; ++j) {
      float x = (c16 < 2) ? Wo[c16 * HDIM + kt * 32 + q * 8 + j] : 0.f;
      wf.s[j] = f2bf(x);
    }
    if (w == 0) sh_wof[kt * 64 + l] = wf.u4;
  }

  // ---- stage context rows (32 rows, hi/lo bf16, stride 264) ----
  for (int e = tid; e < BB * 256; e += 512) {
    int row = e >> 8, col = e & 255;
    float x = ctx[(size_t)(rbase + row) * CTX_DIM + col];
    unsigned short hb = f2bf(x);
    sh_sA[row * 264 + col] = hb;
    sh_sB[row * 264 + col] = f2bf(x - bf2f(hb));
  }
  __syncthreads();

  // ---- h0/c0 = ctx @ Wh.T/Wc.T + bias (3-product split, K=256, 2 groups) ----
  float cst[2][4];   // [group][r]  (raw units)
  {
    f32x4 aH[2] = {{0.f,0.f,0.f,0.f},{0.f,0.f,0.f,0.f}};
    f32x4 aC[2] = {{0.f,0.f,0.f,0.f},{0.f,0.f,0.f,0.f}};
    #pragma unroll
    for (int kt = 0; kt < 8; ++kt) {
      frag_u Ahi[2], Alo[2];
      #pragma unroll
      for (int rt = 0; rt < 2; ++rt) {
        Ahi[rt].u4 = *(const uint4*)&sh_sA[(rt * 16 + c16) * 264 + kt * 32 + q * 8];
        Alo[rt].u4 = *(const uint4*)&sh_sB[(rt * 16 + c16) * 264 + kt * 32 + q * 8];
      }
      frag_u bhi, blo;
      {
        const float* wr = Wh + (size_t)colH * CTX_DIM + kt * 32 + q * 8;
        float4 f0 = *(const float4*)wr;
        float4 f1 = *(const float4*)(wr + 4);
        float ff[8] = {f0.x, f0.y, f0.z, f0.w, f1.x, f1.y, f1.z, f1.w};
        #pragma unroll
        for (int j = 0; j < 8; ++j) {
          unsigned short hb = f2bf(ff[j]);
          bhi.s[j] = hb;
          blo.s[j] = f2bf(ff[j] - bf2f(hb));
        }
      }
      #pragma unroll
      for (int rt = 0; rt < 2; ++rt) {
        aH[rt] = MFMA(Ahi[rt].v, bhi.v, aH[rt]);
        aH[rt] = MFMA(Alo[rt].v, bhi.v, aH[rt]);
        aH[rt] = MFMA(Ahi[rt].v, blo.v, aH[rt]);
      }
      {
        const float* wr = Wc + (size_t)colH * CTX_DIM + kt * 32 + q * 8;
        float4 f0 = *(const float4*)wr;
        float4 f1 = *(const float4*)(wr + 4);
        float ff[8] = {f0.x, f0.y, f0.z, f0.w, f1.x, f1.y, f1.z, f1.w};
        #pragma unroll
        for (int j = 0; j < 8; ++j) {
          unsigned short hb = f2bf(ff[j]);
          bhi.s[j] = hb;
          blo.s[j] = f2bf(ff[j] - bf2f(hb));
        }
      }
      #pragma unroll
      for (int rt = 0; rt < 2; ++rt) {
        aC[rt] = MFMA(Ahi[rt].v, bhi.v, aC[rt]);
        aC[rt] = MFMA(Alo[rt].v, bhi.v, aC[rt]);
        aC[rt] = MFMA(Ahi[rt].v, blo.v, aC[rt]);
      }
    }
    float bhv = bh[colH], bcv = bc[colH];
    float pp0[8][2];
    #pragma unroll
    for (int rt = 0; rt < 2; ++rt) {
      #pragma unroll
      for (int r = 0; r < 4; ++r) {
        float h0v = aH[rt][r] + bhv;
        cst[rt][r] = aC[rt][r] + bcv;
        sh_h[0][(rt * 16 + q * 4 + r) * STR + colH] = (__bf16)h0v;
        pp0[rt * 4 + r][0] = h0v * wo0;
        pp0[rt * 4 + r][1] = h0v * wo1;
      }
    }
    #pragma unroll
    for (int m = 0; m < 8; ++m) {
      pp0[m][0] = row_reduce16(pp0[m][0]);
      pp0[m][1] = row_reduce16(pp0[m][1]);
    }
    if (c16 == 0) {
      #pragma unroll
      for (int rt = 0; rt < 2; ++rt)
        #pragma unroll
        for (int r = 0; r < 4; ++r) {
          sh_pw0[w][(rt * 16 + q * 4 + r) * 2 + 0] = pp0[rt * 4 + r][0];
          sh_pw0[w][(rt * 16 + q * 4 + r) * 2 + 1] = pp0[rt * 4 + r][1];
        }
    }
  }
  __syncthreads();   // sA/sB reuse + pw0 visibility

  // ---- stage static_in = [ball(2), enc(128), pad] (32 rows, stride 168) ----
  for (int e = tid; e < BB * 168; e += 512) {
    int row = e / 168, col = e - row * 168;
    float x = (col < 2) ? ball[(size_t)(rbase + row) * 2 + col]
            : (col < 130) ? enc[(size_t)(rbase + row) * 128 + (col - 2)] : 0.f;
    unsigned short hb = f2bf(x);
    sh_sA[row * 168 + col] = hb;
    sh_sB[row * 168 + col] = f2bf(x - bf2f(hb));
  }
  // virtual pred_{-1} = h0 @ Wo.T + bo (t=0 feedback correction)
  if (tid < BB * 2) {
    float s = (tid & 1) ? bo1 : bo0;
    #pragma unroll
    for (int w2 = 0; w2 < 8; ++w2) s += sh_pw0[w2][tid];
    sh_p0[tid] = s;
  }
  __syncthreads();

  // ---- gate_static (3-product, K=160, SG-scaled) + biases, in REGISTERS ----
  f32x4 gacc[2][4] = {{{0.f,0.f,0.f,0.f},{0.f,0.f,0.f,0.f},{0.f,0.f,0.f,0.f},{0.f,0.f,0.f,0.f}},
                      {{0.f,0.f,0.f,0.f},{0.f,0.f,0.f,0.f},{0.f,0.f,0.f,0.f},{0.f,0.f,0.f,0.f}}};
  #pragma unroll
  for (int kt = 0; kt < 5; ++kt) {
    frag_u Ahi[2], Alo[2];
    #pragma unroll
    for (int rt = 0; rt < 2; ++rt) {
      Ahi[rt].u4 = *(const uint4*)&sh_sA[(rt * 16 + c16) * 168 + kt * 32 + q * 8];
      Alo[rt].u4 = *(const uint4*)&sh_sB[(rt * 16 + c16) * 168 + kt * 32 + q * 8];
    }
    #pragma unroll
    for (int g = 0; g < 4; ++g) {
      frag_u bhi, blo;
      #pragma unroll
      for (int j = 0; j < 8; ++j) {
        int kk = kt * 32 + q * 8 + j;
        float x = (kk < 130) ? SG[g] * W_ih[(size_t)(g * HDIM + colH) * 132 + 2 + kk] : 0.f;
        unsigned short hb = f2bf(x);
        bhi.s[j] = hb;
        blo.s[j] = f2bf(x - bf2f(hb));
      }
      #pragma unroll
      for (int rt = 0; rt < 2; ++rt) {
        gacc[rt][g] = MFMA(Ahi[rt].v, bhi.v, gacc[rt][g]);
        gacc[rt][g] = MFMA(Alo[rt].v, bhi.v, gacc[rt][g]);
        gacc[rt][g] = MFMA(Ahi[rt].v, blo.v, gacc[rt][g]);
      }
    }
  }
  // scaled feedback weights (t=0 correction operates in scaled units)
  float wps0[4], wps1[4];
  #pragma unroll
  for (int g = 0; g < 4; ++g) {
    int colG = g * HDIM + colH;
    float bb = SG[g] * (b_ih[colG] + b_hh[colG] + bo0 * wp0[g] + bo1 * wp1[g]);
    #pragma unroll
    for (int rt = 0; rt < 2; ++rt)
      #pragma unroll
      for (int r = 0; r < 4; ++r) gacc[rt][g][r] += bb;
    wps0[g] = SG[g] * wp0[g];
    wps1[g] = SG[g] * wp1[g];
  }

  // ---- phase-shifted time loop, compile-time buffer parity ----
  // Phase<G,RBUF>(t): MFMA group G gates at time t (reads sh_h[RBUF] rows G),
  //   EW for E=1-G consuming acc[E], writing h_E -> sh_h[(RBUF+G)&1] rows E.
  // One barrier per phase. acc[2][4] carries pending gates across the barrier.
  f32x4 acc[2][4];

  auto phase = [&](auto GC, auto RC, int t, bool doEw, bool corr, bool doPred) {
    constexpr int G = decltype(GC)::value;
    constexpr int E = 1 - G;
    constexpr int RBUF = decltype(RC)::value;
    constexpr int WB = (RBUF + G) & 1;
    const __bf16* hp = &sh_h[RBUF][(G * 16 + c16) * STR];

    // --- MFMA gates for group G at time t; kt=0 consumes gate_static seed
    //     DIRECTLY as the MFMA C operand (no register copy).
    frag_u A[4];
    #pragma unroll
    for (int kt = 0; kt < 4; ++kt)
      A[kt].u4 = *(const uint4*)(hp + kt * 32 + q * 8);
    __builtin_amdgcn_s_setprio(1);
    #pragma unroll
    for (int g = 0; g < 4; ++g)
      acc[G][g] = MFMA(A[0].v, Wf[g][0].v, gacc[G][g]);
    #pragma unroll
    for (int kt = 1; kt < 4; ++kt)
      #pragma unroll
      for (int g = 0; g < 4; ++g)
        acc[G][g] = MFMA(A[kt].v, Wf[g][kt].v, acc[G][g]);

    // --- pred[t-1] rows G = h_G(t) @ Wo (wave 6 for A, wave 7 for B)
    if (doPred && w == 6 + G) {
      f32x4 accP = {0.f, 0.f, 0.f, 0.f};
      #pragma unroll
      for (int kt = 0; kt < 4; ++kt) {
        frag_u wof;
        wof.u4 = sh_wof[kt * 64 + l];
        accP = MFMA(A[kt].v, wof.v, accP);
      }
      if (c16 < 2) {
        const int m0 = G * 16 + q * 4;
        const float bov = c16 ? bo1 : bo0;
        #pragma unroll
        for (int r = 0; r < 4; ++r)
          outp[(size_t)(rbase + m0 + r) * (T_FRAMES * 2) + (t - 1) * 2 + c16] = accP[r] + bov;
      }
    }
    __builtin_amdgcn_s_setprio(0);

    // --- elementwise for group E (independent of this phase's MFMAs)
    //     trans scalar, algebra packed as float2 pairs (v_pk_* on gfx950)
    if (doEw) {
      if (corr) {  // gates at tE==0: remove folded pred_{-1} feedback (scaled)
        #pragma unroll
        for (int r = 0; r < 4; ++r) {
          float2 p0r = *(const float2*)&sh_p0[(E * 16 + q * 4 + r) * 2];
          #pragma unroll
          for (int g = 0; g < 4; ++g)
            acc[E][g][r] -= p0r.x * wps0[g] + p0r.y * wps1[g];
        }
      }
      __bf16* hwp = &sh_h[WB][(E * 16) * STR + colH];
      #pragma unroll
      for (int pr = 0; pr < 2; ++pr) {
        const int r0 = pr * 2, r1 = pr * 2 + 1;
        f32x2 ei = { EXP2(-acc[E][0][r0]), EXP2(-acc[E][0][r1]) };   // e^{-i}
        f32x2 ef = { EXP2(-acc[E][1][r0]), EXP2(-acc[E][1][r1]) };   // e^{-f}
        f32x2 eg = { EXP2(-acc[E][2][r0]), EXP2(-acc[E][2][r1]) };   // e^{-2g}
        f32x2 eo = { EXP2(-acc[E][3][r0]), EXP2(-acc[E][3][r1]) };   // e^{-o}
        f32x2 t1 = (1.f + ei) * (1.f + eg);
        f32x2 pf = 1.f + ef;
        f32x2 cp = { cst[E][r0], cst[E][r1] };
        f32x2 num = cp * t1 + (1.f - eg) * pf;
        f32x2 den = t1 * pf;
        f32x2 cv = num * (f32x2){ RCP(den.x), RCP(den.y) };
        cst[E][r0] = cv.x;
        cst[E][r1] = cv.y;
        f32x2 cc = { fmaxf(cv.x, -15.f), fmaxf(cv.y, -15.f) };       // -inf guard
        cc = cc * (-2.f * 1.4426950408889634f);
        f32x2 ec = { EXP2(cc.x), EXP2(cc.y) };
        f32x2 d2 = (1.f + eo) * (1.f + ec);
        f32x2 hv = (1.f - ec) * (f32x2){ RCP(d2.x), RCP(d2.y) };
        hwp[(q * 4 + r0) * STR] = (__bf16)hv.x;
        hwp[(q * 4 + r1) * STR] = (__bf16)hv.y;
      }
    }
    __syncthreads();
  };

  phase(Int<0>{}, Int<0>{}, 0, false, false, false);   // MFMA A(0)
  phase(Int<1>{}, Int<0>{}, 0, true,  true,  false);   // MFMA B(0); ew A(0)+corr -> h_A(1)
  phase(Int<0>{}, Int<1>{}, 1, true,  true,  true);    // MFMA A(1); ew B(0)+corr -> h_B(1); pred[0]A
  for (int tp = 0; tp < 63; ++tp) {
    const int t = 2 * tp + 1;
    phase(Int<1>{}, Int<1>{}, t,     true, false, true);   // MFMA B(t);   ew A(t)   -> h_A(t+1)
    phase(Int<0>{}, Int<0>{}, t + 1, true, false, true);   // MFMA A(t+1); ew B(t)   -> h_B(t+1)
    phase(Int<1>{}, Int<0>{}, t + 1, true, false, true);   // MFMA B(t+1); ew A(t+1) -> h_A(t+2)
    phase(Int<0>{}, Int<1>{}, t + 2, true, false, true);   // MFMA A(t+2); ew B(t+1) -> h_B(t+2)
  }
  phase(Int<1>{}, Int<1>{}, 127, true, false, true);   // MFMA B(127); ew A(127) -> h_A(128); pred[126]B

  // final elementwise: B(127) -> h_B(128) into buf[0]
  {
    __bf16* hwp = &sh_h[0][16 * STR + colH];
    #pragma unroll
    for (int r = 0; r < 4; ++r) {
      float ei = EXP2(-acc[1][0][r]);
      float ef = EXP2(-acc[1][1][r]);
      float eg = EXP2(-acc[1][2][r]);
      float eo = EXP2(-acc[1][3][r]);
      float t1 = (1.f + ei) * (1.f + eg);
      float pf = 1.f + ef;
      float num = cst[1][r] * t1 + (1.f - eg) * pf;
      float cv = num * RCP(t1 * pf);
      float cc = fmaxf(cv, -15.f);
      float ec = EXP2(cc * (-2.f * 1.4426950408889634f));
      float hv = (1.f - ec) * RCP((1.f + eo) * (1.f + ec));
      hwp[(q * 4 + r) * STR] = (__bf16)hv;
    }
  }
  __syncthreads();

  // ---- epilogue: pred[127] from h(128) (buf 0), waves 6 (A) / 7 (B) ----
  if (w == 6 || w == 7) {
    const int Ge = w - 6;
    const __bf16* hp = &sh_h[0][(Ge * 16 + c16) * STR];
    f32x4 accP = {0.f, 0.f, 0.f, 0.f};
    #pragma unroll
    for (int kt = 0; kt < 4; ++kt) {
      frag_u A, wof;
      A.u4 = *(const uint4*)(hp + kt * 32 + q * 8);
      wof.u4 = sh_wof[kt * 64 + l];
      accP = MFMA(A.v, wof.v, accP);
    }
    if (c16 < 2) {
      const int m0 = Ge * 16 + q * 4;
      const float bov = c16 ? bo1 : bo0;
      #pragma unroll
      for (int r = 0; r < 4; ++r)
        outp[(size_t)(rbase + m0 + r) * (T_FRAMES * 2) + 127 * 2 + c16] = accP[r] + bov;
    }
  }
}

extern "C" void kernel_launch(void* const* d_in, const int* in_sizes, int n_in,
                              void* d_out, int out_size, void* d_ws, size_t ws_size,
                              hipStream_t stream) {
  (void)in_sizes; (void)n_in; (void)d_ws; (void)ws_size; (void)out_size;
  const float* ctx  = (const float*)d_in[0];
  const float* enc  = (const float*)d_in[1];
  const float* ball = (const float*)d_in[2];
  // d_in[3] = max_frames (always 128)
  const float* Wh   = (const float*)d_in[4];
  const float* bh   = (const float*)d_in[5];
  const float* Wc   = (const float*)d_in[6];
  const float* bc   = (const float*)d_in[7];
  const float* W_ih = (const float*)d_in[8];
  const float* W_hh = (const float*)d_in[9];
  const float* b_ih = (const float*)d_in[10];
  const float* b_hh = (const float*)d_in[11];
  const float* Wo   = (const float*)d_in[12];
  const float* bo   = (const float*)d_in[13];
  float* outp = (float*)d_out;

  dim3 grid(256), block(512);
  traj_lstm<<<grid, block, 0, stream>>>(ctx, enc, ball, Wh, bh, Wc, bc,
                                        W_ih, W_hh, b_ih, b_hh, Wo, bo, outp);
}

// Round 14
// 288.089 us; speedup vs baseline: 1.1290x; 1.0268x over previous
//
#include <hip/hip_runtime.h>
#include <hip/hip_bf16.h>

// TrajectoryDecoder: B=8192 LSTM, T=128, H=128, CTX=256, IN_DIM=132.
// R24 = R20/R23 loop (session best, 252us steady) + setup spill fix.
// R23 consolidation exposed the anomaly: WRITE_SIZE 36.9MB vs 8.4MB actual
// output (FETCH 23.7 vs ~15MB inputs), while R17's 256-thread variant was
// exactly clean (8.2/9.7) -> the 512-thread structure spills ~220B/thread
// in SETUP on every dispatch. Mechanism: Wf[4][4] (64 VGPRs) was built
// FIRST and held live through the register-heaviest setup section (h0/c0
// GEMM: frag pairs + hi/lo splits + dual accs + temps ~70 regs) -> peak
// ~140 regs vs the 128 working set -> scratch. Fix is pure code motion:
//  - Wf build moved to AFTER gate_static (last thing before the loop);
//    it reads only globals, no staged-data dependence.
//  - wp0/wp1 live range narrowed to bias-fold + Wf build.
// Loop is byte-identical to R20/R23: 512 thr, 1 block/CU, phase-shifted
// A/B groups, compile-time RBUF parity, setprio on MFMA, direct C-seed,
// float2-packed EW, exp2 prescale SG={L,L,2L,L}, in-loop pred stores.

#define HDIM 128
#define CTX_DIM 256
#define T_FRAMES 128
#define BB 32     // batch rows per block
#define STR 136   // h row stride (elements); 272B rows keep 16B alignment

typedef __bf16 bf16x8 __attribute__((ext_vector_type(8)));
typedef float  f32x4  __attribute__((ext_vector_type(4)));
typedef float  f32x2  __attribute__((ext_vector_type(2)));

union frag_u {
  bf16x8 v;
  unsigned short s[8];
  uint4 u4;
};

#if __has_builtin(__builtin_amdgcn_exp2f)
#define EXP2(x) __builtin_amdgcn_exp2f(x)
#else
#define EXP2(x) __expf((x) * 0.6931471805599453f)
#endif
#define RCP(x) __builtin_amdgcn_rcpf(x)

__device__ __forceinline__ unsigned short f2bf(float x) {
  unsigned u = __builtin_bit_cast(unsigned, x);
  u += 0x7FFFu + ((u >> 16) & 1u);          // RNE to bf16
  return (unsigned short)(u >> 16);
}
__device__ __forceinline__ float bf2f(unsigned short h) {
  unsigned u = ((unsigned)h) << 16;
  return __builtin_bit_cast(float, u);
}
template<int CTRL>
__device__ __forceinline__ float dpp_mov(float x) {
  return __builtin_bit_cast(float,
    __builtin_amdgcn_mov_dpp(__builtin_bit_cast(int, x), CTRL, 0xF, 0xF, true));
}
// sum over the 16-lane row group (setup-only)
__device__ __forceinline__ float row_reduce16(float v) {
  v += dpp_mov<0xB1>(v);     // quad_perm xor1
  v += dpp_mov<0x4E>(v);     // quad_perm xor2
  v += dpp_mov<0x124>(v);    // row_ror:4
  v += dpp_mov<0x128>(v);    // row_ror:8
  return v;
}

template<int N> struct Int { static constexpr int value = N; };

#define MFMA(a, b, c) __builtin_amdgcn_mfma_f32_16x16x32_bf16((a), (b), (c), 0, 0, 0)

__global__ __launch_bounds__(512, 1) void traj_lstm(
    const float* __restrict__ ctx, const float* __restrict__ enc,
    const float* __restrict__ ball,
    const float* __restrict__ Wh, const float* __restrict__ bh,
    const float* __restrict__ Wc, const float* __restrict__ bc,
    const float* __restrict__ W_ih, const float* __restrict__ W_hh,
    const float* __restrict__ b_ih, const float* __restrict__ b_hh,
    const float* __restrict__ Wo, const float* __restrict__ bo,
    float* __restrict__ outp)
{
  __shared__ __align__(16) __bf16 sh_h[2][BB * STR];          // h double buffer (17.4 KB)
  __shared__ __align__(16) unsigned short sh_sA[BB * 264];    // setup staging hi (16.9 KB)
  __shared__ __align__(16) unsigned short sh_sB[BB * 264];    // setup staging lo (16.9 KB)
  __shared__ __align__(16) uint4 sh_wof[4 * 64];              // Wo B-frags (4 KB)
  __shared__ float sh_pw0[8][BB * 2];     // setup pred partials (2 KB)
  __shared__ float sh_p0[BB * 2];         // virtual pred_{-1} for t=0 correction

  const int tid  = threadIdx.x;
  const int w    = tid >> 6;
  const int l    = tid & 63;
  const int q    = l >> 4;
  const int c16  = l & 15;
  const int colH = w * 16 + c16;
  const int rbase = blockIdx.x * BB;

  const float Lc = 1.4426950408889634f;          // log2(e)
  const float SG[4] = {Lc, Lc, 2.f * Lc, Lc};    // i, f, g, o exp2 prescales
  const float bo0 = bo[0], bo1 = bo[1];
  const float wo0 = Wo[colH], wo1 = Wo[HDIM + colH];

  // ---- Wo B-fragments for the pred MFMA -> LDS (waves 6/7 read) ----
  #pragma unroll
  for (int kt = 0; kt < 4; ++kt) {
    frag_u wf;
    #pragma unroll
    for (int j = 0; j < 8; ++j) {
      float x = (c16 < 2) ? Wo[c16 * HDIM + kt * 32 + q * 8 + j] : 0.f;
      wf.s[j] = f2bf(x);
    }
    if (w == 0) sh_wof[kt * 64 + l] = wf.u4;
  }

  // ---- stage context rows (32 rows, hi/lo bf16, stride 264) ----
  for (int e = tid; e < BB * 256; e += 512) {
    int row = e >> 8, col = e & 255;
    float x = ctx[(size_t)(rbase + row) * CTX_DIM + col];
    unsigned short hb = f2bf(x);
    sh_sA[row * 264 + col] = hb;
    sh_sB[row * 264 + col] = f2bf(x - bf2f(hb));
  }
  __syncthreads();

  // ---- h0/c0 = ctx @ Wh.T/Wc.T + bias (3-product split, K=256, 2 groups) ----
  // NOTE: Wf is NOT yet live here -- this is the register-heaviest section
  // and previously spilled ~220B/thread with Wf[4][4] resident.
  float cst[2][4];   // [group][r]  (raw units)
  {
    f32x4 aH[2] = {{0.f,0.f,0.f,0.f},{0.f,0.f,0.f,0.f}};
    f32x4 aC[2] = {{0.f,0.f,0.f,0.f},{0.f,0.f,0.f,0.f}};
    #pragma unroll
    for (int kt = 0; kt < 8; ++kt) {
      frag_u Ahi[2], Alo[2];
      #pragma unroll
      for (int rt = 0; rt < 2; ++rt) {
        Ahi[rt].u4 = *(const uint4*)&sh_sA[(rt * 16 + c16) * 264 + kt * 32 + q * 8];
        Alo[rt].u4 = *(const uint4*)&sh_sB[(rt * 16 + c16) * 264 + kt * 32 + q * 8];
      }
      frag_u bhi, blo;
      {
        const float* wr = Wh + (size_t)colH * CTX_DIM + kt * 32 + q * 8;
        float4 f0 = *(const float4*)wr;
        float4 f1 = *(const float4*)(wr + 4);
        float ff[8] = {f0.x, f0.y, f0.z, f0.w, f1.x, f1.y, f1.z, f1.w};
        #pragma unroll
        for (int j = 0; j < 8; ++j) {
          unsigned short hb = f2bf(ff[j]);
          bhi.s[j] = hb;
          blo.s[j] = f2bf(ff[j] - bf2f(hb));
        }
      }
      #pragma unroll
      for (int rt = 0; rt < 2; ++rt) {
        aH[rt] = MFMA(Ahi[rt].v, bhi.v, aH[rt]);
        aH[rt] = MFMA(Alo[rt].v, bhi.v, aH[rt]);
        aH[rt] = MFMA(Ahi[rt].v, blo.v, aH[rt]);
      }
      {
        const float* wr = Wc + (size_t)colH * CTX_DIM + kt * 32 + q * 8;
        float4 f0 = *(const float4*)wr;
        float4 f1 = *(const float4*)(wr + 4);
        float ff[8] = {f0.x, f0.y, f0.z, f0.w, f1.x, f1.y, f1.z, f1.w};
        #pragma unroll
        for (int j = 0; j < 8; ++j) {
          unsigned short hb = f2bf(ff[j]);
          bhi.s[j] = hb;
          blo.s[j] = f2bf(ff[j] - bf2f(hb));
        }
      }
      #pragma unroll
      for (int rt = 0; rt < 2; ++rt) {
        aC[rt] = MFMA(Ahi[rt].v, bhi.v, aC[rt]);
        aC[rt] = MFMA(Alo[rt].v, bhi.v, aC[rt]);
        aC[rt] = MFMA(Ahi[rt].v, blo.v, aC[rt]);
      }
    }
    float bhv = bh[colH], bcv = bc[colH];
    float pp0[8][2];
    #pragma unroll
    for (int rt = 0; rt < 2; ++rt) {
      #pragma unroll
      for (int r = 0; r < 4; ++r) {
        float h0v = aH[rt][r] + bhv;
        cst[rt][r] = aC[rt][r] + bcv;
        sh_h[0][(rt * 16 + q * 4 + r) * STR + colH] = (__bf16)h0v;
        pp0[rt * 4 + r][0] = h0v * wo0;
        pp0[rt * 4 + r][1] = h0v * wo1;
      }
    }
    #pragma unroll
    for (int m = 0; m < 8; ++m) {
      pp0[m][0] = row_reduce16(pp0[m][0]);
      pp0[m][1] = row_reduce16(pp0[m][1]);
    }
    if (c16 == 0) {
      #pragma unroll
      for (int rt = 0; rt < 2; ++rt)
        #pragma unroll
        for (int r = 0; r < 4; ++r) {
          sh_pw0[w][(rt * 16 + q * 4 + r) * 2 + 0] = pp0[rt * 4 + r][0];
          sh_pw0[w][(rt * 16 + q * 4 + r) * 2 + 1] = pp0[rt * 4 + r][1];
        }
    }
  }
  __syncthreads();   // sA/sB reuse + pw0 visibility

  // ---- stage static_in = [ball(2), enc(128), pad] (32 rows, stride 168) ----
  for (int e = tid; e < BB * 168; e += 512) {
    int row = e / 168, col = e - row * 168;
    float x = (col < 2) ? ball[(size_t)(rbase + row) * 2 + col]
            : (col < 130) ? enc[(size_t)(rbase + row) * 128 + (col - 2)] : 0.f;
    unsigned short hb = f2bf(x);
    sh_sA[row * 168 + col] = hb;
    sh_sB[row * 168 + col] = f2bf(x - bf2f(hb));
  }
  // virtual pred_{-1} = h0 @ Wo.T + bo (t=0 feedback correction)
  if (tid < BB * 2) {
    float s = (tid & 1) ? bo1 : bo0;
    #pragma unroll
    for (int w2 = 0; w2 < 8; ++w2) s += sh_pw0[w2][tid];
    sh_p0[tid] = s;
  }
  __syncthreads();

  // ---- gate_static (3-product, K=160, SG-scaled) + biases, in REGISTERS ----
  f32x4 gacc[2][4] = {{{0.f,0.f,0.f,0.f},{0.f,0.f,0.f,0.f},{0.f,0.f,0.f,0.f},{0.f,0.f,0.f,0.f}},
                      {{0.f,0.f,0.f,0.f},{0.f,0.f,0.f,0.f},{0.f,0.f,0.f,0.f},{0.f,0.f,0.f,0.f}}};
  #pragma unroll
  for (int kt = 0; kt < 5; ++kt) {
    frag_u Ahi[2], Alo[2];
    #pragma unroll
    for (int rt = 0; rt < 2; ++rt) {
      Ahi[rt].u4 = *(const uint4*)&sh_sA[(rt * 16 + c16) * 168 + kt * 32 + q * 8];
      Alo[rt].u4 = *(const uint4*)&sh_sB[(rt * 16 + c16) * 168 + kt * 32 + q * 8];
    }
    #pragma unroll
    for (int g = 0; g < 4; ++g) {
      frag_u bhi, blo;
      #pragma unroll
      for (int j = 0; j < 8; ++j) {
        int kk = kt * 32 + q * 8 + j;
        float x = (kk < 130) ? SG[g] * W_ih[(size_t)(g * HDIM + colH) * 132 + 2 + kk] : 0.f;
        unsigned short hb = f2bf(x);
        bhi.s[j] = hb;
        blo.s[j] = f2bf(x - bf2f(hb));
      }
      #pragma unroll
      for (int rt = 0; rt < 2; ++rt) {
        gacc[rt][g] = MFMA(Ahi[rt].v, bhi.v, gacc[rt][g]);
        gacc[rt][g] = MFMA(Alo[rt].v, bhi.v, gacc[rt][g]);
        gacc[rt][g] = MFMA(Ahi[rt].v, blo.v, gacc[rt][g]);
      }
    }
  }

  // ---- feedback weights (narrow live range: bias fold + Wf build only) ----
  float wp0[4], wp1[4];
  #pragma unroll
  for (int g = 0; g < 4; ++g) {
    wp0[g] = W_ih[(size_t)(g * HDIM + colH) * 132 + 0];
    wp1[g] = W_ih[(size_t)(g * HDIM + colH) * 132 + 1];
  }
  // scaled feedback weights (t=0 correction operates in scaled units)
  float wps0[4], wps1[4];
  #pragma unroll
  for (int g = 0; g < 4; ++g) {
    int colG = g * HDIM + colH;
    float bb = SG[g] * (b_ih[colG] + b_hh[colG] + bo0 * wp0[g] + bo1 * wp1[g]);
    #pragma unroll
    for (int rt = 0; rt < 2; ++rt)
      #pragma unroll
      for (int r = 0; r < 4; ++r) gacc[rt][g][r] += bb;
    wps0[g] = SG[g] * wp0[g];
    wps1[g] = SG[g] * wp1[g];
  }

  // ---- persistent W_eff fragments: SG[g]*(W_hh + wp0*Wo0 + wp1*Wo1) ----
  // Built LAST so the 64 VGPRs are not live through the setup GEMMs.
  frag_u Wf[4][4];                  // [gate][ktile]  (64 VGPRs)
  #pragma unroll
  for (int kt = 0; kt < 4; ++kt) {
    const float* w0p = Wo + kt * 32 + q * 8;
    const float* w1p = Wo + HDIM + kt * 32 + q * 8;
    float4 a0 = *(const float4*)w0p, a1 = *(const float4*)(w0p + 4);
    float4 b0 = *(const float4*)w1p, b1 = *(const float4*)(w1p + 4);
    float wo0v[8] = {a0.x, a0.y, a0.z, a0.w, a1.x, a1.y, a1.z, a1.w};
    float wo1v[8] = {b0.x, b0.y, b0.z, b0.w, b1.x, b1.y, b1.z, b1.w};
    #pragma unroll
    for (int g = 0; g < 4; ++g) {
      const float* wr = W_hh + (size_t)(g * HDIM + colH) * HDIM + kt * 32 + q * 8;
      float4 f0 = *(const float4*)wr;
      float4 f1 = *(const float4*)(wr + 4);
      float ff[8] = {f0.x, f0.y, f0.z, f0.w, f1.x, f1.y, f1.z, f1.w};
      #pragma unroll
      for (int j = 0; j < 8; ++j)
        Wf[g][kt].s[j] = f2bf(SG[g] * (ff[j] + wp0[g] * wo0v[j] + wp1[g] * wo1v[j]));
    }
  }

  // ---- phase-shifted time loop, compile-time buffer parity ----
  // Phase<G,RBUF>(t): MFMA group G gates at time t (reads sh_h[RBUF] rows G),
  //   EW for E=1-G consuming acc[E], writing h_E -> sh_h[(RBUF+G)&1] rows E.
  // One barrier per phase. acc[2][4] carries pending gates across the barrier.
  f32x4 acc[2][4];

  auto phase = [&](auto GC, auto RC, int t, bool doEw, bool corr, bool doPred) {
    constexpr int G = decltype(GC)::value;
    constexpr int E = 1 - G;
    constexpr int RBUF = decltype(RC)::value;
    constexpr int WB = (RBUF + G) & 1;
    const __bf16* hp = &sh_h[RBUF][(G * 16 + c16) * STR];

    // --- MFMA gates for group G at time t; kt=0 consumes gate_static seed
    //     DIRECTLY as the MFMA C operand (no register copy).
    frag_u A[4];
    #pragma unroll
    for (int kt = 0; kt < 4; ++kt)
      A[kt].u4 = *(const uint4*)(hp + kt * 32 + q * 8);
    __builtin_amdgcn_s_setprio(1);
    #pragma unroll
    for (int g = 0; g < 4; ++g)
      acc[G][g] = MFMA(A[0].v, Wf[g][0].v, gacc[G][g]);
    #pragma unroll
    for (int kt = 1; kt < 4; ++kt)
      #pragma unroll
      for (int g = 0; g < 4; ++g)
        acc[G][g] = MFMA(A[kt].v, Wf[g][kt].v, acc[G][g]);

    // --- pred[t-1] rows G = h_G(t) @ Wo (wave 6 for A, wave 7 for B)
    if (doPred && w == 6 + G) {
      f32x4 accP = {0.f, 0.f, 0.f, 0.f};
      #pragma unroll
      for (int kt = 0; kt < 4; ++kt) {
        frag_u wof;
        wof.u4 = sh_wof[kt * 64 + l];
        accP = MFMA(A[kt].v, wof.v, accP);
      }
      if (c16 < 2) {
        const int m0 = G * 16 + q * 4;
        const float bov = c16 ? bo1 : bo0;
        #pragma unroll
        for (int r = 0; r < 4; ++r)
          outp[(size_t)(rbase + m0 + r) * (T_FRAMES * 2) + (t - 1) * 2 + c16] = accP[r] + bov;
      }
    }
    __builtin_amdgcn_s_setprio(0);

    // --- elementwise for group E (independent of this phase's MFMAs)
    //     trans scalar, algebra packed as float2 pairs (v_pk_* on gfx950)
    if (doEw) {
      if (corr) {  // gates at tE==0: remove folded pred_{-1} feedback (scaled)
        #pragma unroll
        for (int r = 0; r < 4; ++r) {
          float2 p0r = *(const float2*)&sh_p0[(E * 16 + q * 4 + r) * 2];
          #pragma unroll
          for (int g = 0; g < 4; ++g)
            acc[E][g][r] -= p0r.x * wps0[g] + p0r.y * wps1[g];
        }
      }
      __bf16* hwp = &sh_h[WB][(E * 16) * STR + colH];
      #pragma unroll
      for (int pr = 0; pr < 2; ++pr) {
        const int r0 = pr * 2, r1 = pr * 2 + 1;
        f32x2 ei = { EXP2(-acc[E][0][r0]), EXP2(-acc[E][0][r1]) };   // e^{-i}
        f32x2 ef = { EXP2(-acc[E][1][r0]), EXP2(-acc[E][1][r1]) };   // e^{-f}
        f32x2 eg = { EXP2(-acc[E][2][r0]), EXP2(-acc[E][2][r1]) };   // e^{-2g}
        f32x2 eo = { EXP2(-acc[E][3][r0]), EXP2(-acc[E][3][r1]) };   // e^{-o}
        f32x2 t1 = (1.f + ei) * (1.f + eg);
        f32x2 pf = 1.f + ef;
        f32x2 cp = { cst[E][r0], cst[E][r1] };
        f32x2 num = cp * t1 + (1.f - eg) * pf;
        f32x2 den = t1 * pf;
        f32x2 cv = num * (f32x2){ RCP(den.x), RCP(den.y) };
        cst[E][r0] = cv.x;
        cst[E][r1] = cv.y;
        f32x2 cc = { fmaxf(cv.x, -15.f), fmaxf(cv.y, -15.f) };       // -inf guard
        cc = cc * (-2.f * 1.4426950408889634f);
        f32x2 ec = { EXP2(cc.x), EXP2(cc.y) };
        f32x2 d2 = (1.f + eo) * (1.f + ec);
        f32x2 hv = (1.f - ec) * (f32x2){ RCP(d2.x), RCP(d2.y) };
        hwp[(q * 4 + r0) * STR] = (__bf16)hv.x;
        hwp[(q * 4 + r1) * STR] = (__bf16)hv.y;
      }
    }
    __syncthreads();
  };

  phase(Int<0>{}, Int<0>{}, 0, false, false, false);   // MFMA A(0)
  phase(Int<1>{}, Int<0>{}, 0, true,  true,  false);   // MFMA B(0); ew A(0)+corr -> h_A(1)
  phase(Int<0>{}, Int<1>{}, 1, true,  true,  true);    // MFMA A(1); ew B(0)+corr -> h_B(1); pred[0]A
  for (int tp = 0; tp < 63; ++tp) {
    const int t = 2 * tp + 1;
    phase(Int<1>{}, Int<1>{}, t,     true, false, true);   // MFMA B(t);   ew A(t)   -> h_A(t+1)
    phase(Int<0>{}, Int<0>{}, t + 1, true, false, true);   // MFMA A(t+1); ew B(t)   -> h_B(t+1)
    phase(Int<1>{}, Int<0>{}, t + 1, true, false, true);   // MFMA B(t+1); ew A(t+1) -> h_A(t+2)
    phase(Int<0>{}, Int<1>{}, t + 2, true, false, true);   // MFMA A(t+2); ew B(t+1) -> h_B(t+2)
  }
  phase(Int<1>{}, Int<1>{}, 127, true, false, true);   // MFMA B(127); ew A(127) -> h_A(128); pred[126]B

  // final elementwise: B(127) -> h_B(128) into buf[0]
  {
    __bf16* hwp = &sh_h[0][16 * STR + colH];
    #pragma unroll
    for (int r = 0; r < 4; ++r) {
      float ei = EXP2(-acc[1][0][r]);
      float ef = EXP2(-acc[1][1][r]);
      float eg = EXP2(-acc[1][2][r]);
      float eo = EXP2(-acc[1][3][r]);
      float t1 = (1.f + ei) * (1.f + eg);
      float pf = 1.f + ef;
      float num = cst[1][r] * t1 + (1.f - eg) * pf;
      float cv = num * RCP(t1 * pf);
      float cc = fmaxf(cv, -15.f);
      float ec = EXP2(cc * (-2.f * 1.4426950408889634f));
      float hv = (1.f - ec) * RCP((1.f + eo) * (1.f + ec));
      hwp[(q * 4 + r) * STR] = (__bf16)hv;
    }
  }
  __syncthreads();

  // ---- epilogue: pred[127] from h(128) (buf 0), waves 6 (A) / 7 (B) ----
  if (w == 6 || w == 7) {
    const int Ge = w - 6;
    const __bf16* hp = &sh_h[0][(Ge * 16 + c16) * STR];
    f32x4 accP = {0.f, 0.f, 0.f, 0.f};
    #pragma unroll
    for (int kt = 0; kt < 4; ++kt) {
      frag_u A, wof;
      A.u4 = *(const uint4*)(hp + kt * 32 + q * 8);
      wof.u4 = sh_wof[kt * 64 + l];
      accP = MFMA(A.v, wof.v, accP);
    }
    if (c16 < 2) {
      const int m0 = Ge * 16 + q * 4;
      const float bov = c16 ? bo1 : bo0;
      #pragma unroll
      for (int r = 0; r < 4; ++r)
        outp[(size_t)(rbase + m0 + r) * (T_FRAMES * 2) + 127 * 2 + c16] = accP[r] + bov;
    }
  }
}

extern "C" void kernel_launch(void* const* d_in, const int* in_sizes, int n_in,
                              void* d_out, int out_size, void* d_ws, size_t ws_size,
                              hipStream_t stream) {
  (void)in_sizes; (void)n_in; (void)d_ws; (void)ws_size; (void)out_size;
  const float* ctx  = (const float*)d_in[0];
  const float* enc  = (const float*)d_in[1];
  const float* ball = (const float*)d_in[2];
  // d_in[3] = max_frames (always 128)
  const float* Wh   = (const float*)d_in[4];
  const float* bh   = (const float*)d_in[5];
  const float* Wc   = (const float*)d_in[6];
  const float* bc   = (const float*)d_in[7];
  const float* W_ih = (const float*)d_in[8];
  const float* W_hh = (const float*)d_in[9];
  const float* b_ih = (const float*)d_in[10];
  const float* b_hh = (const float*)d_in[11];
  const float* Wo   = (const float*)d_in[12];
  const float* bo   = (const float*)d_in[13];
  float* outp = (float*)d_out;

  dim3 grid(256), block(512);
  traj_lstm<<<grid, block, 0, stream>>>(ctx, enc, ball, Wh, bh, Wc, bc,
                                        W_ih, W_hh, b_ih, b_hh, Wo, bo, outp);
}